// Round 12
// baseline (56.375 us; speedup 1.0000x reference)
//
#include <hip/hip_runtime.h>

#define NE 8               // experts
#define H4 512             // float4 per token row (2048 floats)
#define NTOK 16384         // 4 * 4096 tokens
#define QK 2               // K halves, one per 4-wave team
#define ITQ (8 / QK)       // 64-col it-steps per half = 4
#define TPW 4              // tokens per wave
#define TPB 16             // tokens per block
#define NBLK_A (NTOK / TPB)  // 1024 blocks
#define AUX_COEF 0.01f

typedef float f4v __attribute__((ext_vector_type(4)));

// 8-leaf static-index select (rule #20: no runtime array indexing)
#define SEL8(A) ((e2 & 4) ? ((e2 & 2) ? ((e2 & 1) ? A[7] : A[6])   \
                                      : ((e2 & 1) ? A[5] : A[4]))  \
                          : ((e2 & 2) ? ((e2 & 1) ? A[3] : A[2])   \
                                      : ((e2 & 1) ? A[1] : A[0])))

// Fused router: 512 threads = 2 half-K teams of 4 waves; each wave's
// streaming workload is identical to R11's proven kernel A. Halves combine
// through 1 KB LDS, then every thread redundantly finishes its token
// (softmax/top-2), writers emit outputs + per-block aux partials.
__global__ __launch_bounds__(512)
void router_fused(const float* __restrict__ hs, const float* __restrict__ gw,
                  float* __restrict__ out, float* __restrict__ ws2)
{
    __shared__ float4 comb4[QK][TPB][2];     // [q][token][8 floats]
    __shared__ float  auxS[TPB][16];

    const int tid  = threadIdx.x;
    const int wave = tid >> 6, lane = tid & 63;
    const int q    = wave >> 2;              // K-half team
    const int wv   = wave & 3;               // wave within team
    const int tok0 = blockIdx.x * TPB + wv * TPW;

    const f4v* __restrict__ hs4 = (const f4v*)hs;
    const f4v* __restrict__ gw4 = (const f4v*)gw;

    float acc[TPW][NE];
    #pragma unroll
    for (int r = 0; r < TPW; ++r)
        #pragma unroll
        for (int e = 0; e < NE; ++e) acc[r][e] = 0.f;

    #pragma unroll
    for (int it = 0; it < ITQ; ++it) {
        const int col = q * (H4 / QK) + it * 64 + lane;
        f4v h[TPW];
        #pragma unroll
        for (int r = 0; r < TPW; ++r)
            h[r] = hs4[(size_t)(tok0 + r) * H4 + col];
        f4v g[NE];
        #pragma unroll
        for (int e = 0; e < NE; ++e) g[e] = gw4[e * H4 + col];
        #pragma unroll
        for (int r = 0; r < TPW; ++r)
            #pragma unroll
            for (int e = 0; e < NE; ++e)
                acc[r][e] += h[r].x * g[e].x + h[r].y * g[e].y
                           + h[r].z * g[e].z + h[r].w * g[e].w;
    }

    // butterfly: every lane gets the full half-dot for all 32 (r,e)
    #pragma unroll
    for (int r = 0; r < TPW; ++r)
        #pragma unroll
        for (int e = 0; e < NE; ++e) {
            float v = acc[r][e];
            #pragma unroll
            for (int s = 32; s > 0; s >>= 1) v += __shfl_xor(v, s, 64);
            acc[r][e] = v;
        }

    // lanes 0..31: one (token,expert) partial each -> LDS (conflict-free)
    {
        const int r2 = (lane >> 3) & 3, e2 = lane & 7;
        const float v = (r2 & 2) ? ((r2 & 1) ? SEL8(acc[3]) : SEL8(acc[2]))
                                 : ((r2 & 1) ? SEL8(acc[1]) : SEL8(acc[0]));
        float* combf = (float*)comb4;
        if (lane < 32)
            combf[(q * TPB + wv * TPW + r2) * NE + e2] = v;
    }
    __syncthreads();

    // every thread finishes token t = tid>>5 redundantly (32 threads/token)
    const int t = tid >> 5;
    float lg[NE];
    {
        const float4 a0 = comb4[0][t][0], a1 = comb4[0][t][1];
        const float4 b0 = comb4[1][t][0], b1 = comb4[1][t][1];
        lg[0]=a0.x+b0.x; lg[1]=a0.y+b0.y; lg[2]=a0.z+b0.z; lg[3]=a0.w+b0.w;
        lg[4]=a1.x+b1.x; lg[5]=a1.y+b1.y; lg[6]=a1.z+b1.z; lg[7]=a1.w+b1.w;
    }

    float m = lg[0];
    #pragma unroll
    for (int e = 1; e < NE; ++e) m = fmaxf(m, lg[e]);
    float p[NE];
    float s = 0.f;
    #pragma unroll
    for (int e = 0; e < NE; ++e) { p[e] = __expf(lg[e] - m); s += p[e]; }
    const float inv = 1.f / s;

    // top-2 on probs; strict '>' keeps lowest index on ties (lax.top_k order)
    float v0 = -1.f; int i0 = 0;
    #pragma unroll
    for (int e = 0; e < NE; ++e) { if (p[e] > v0) { v0 = p[e]; i0 = e; } }
    float v1 = -1.f; int i1 = 0;
    #pragma unroll
    for (int e = 0; e < NE; ++e) { if (e != i0 && p[e] > v1) { v1 = p[e]; i1 = e; } }

    if ((tid & 31) == 0) {
        const int tok = blockIdx.x * TPB + t;
        float2* __restrict__ o2 = (float2*)out;
        const float wsum = v0 + v1;
        o2[tok]        = make_float2(v0 / wsum, v1 / wsum);
        o2[NTOK + tok] = make_float2((float)i0, (float)i1);
        #pragma unroll
        for (int e = 0; e < NE; ++e) {
            auxS[t][e]      = p[e] * inv;
            auxS[t][NE + e] = ((i0 == e) ? 1.f : 0.f) + ((i1 == e) ? 1.f : 0.f);
        }
    }
    __syncthreads();

    // per-block aux partial: sum 16 token-rows -> ws2[block][0..15]
    if (tid < 16) {
        float sum = 0.f;
        #pragma unroll
        for (int t2 = 0; t2 < TPB; ++t2) sum += auxS[t2][tid];
        ws2[blockIdx.x * 16 + tid] = sum;
    }
}

// Reduce 1024 x 16 partials -> aux scalar
__global__ __launch_bounds__(256)
void router_aux2(const float* __restrict__ ws2, float* __restrict__ out)
{
    __shared__ float red[16][16];
    __shared__ float tot[16];
    const int tid = threadIdx.x;
    const int e = tid & 15, row = tid >> 4;      // 16 rows x 16
    float s = 0.f;
    #pragma unroll 4
    for (int k = 0; k < NBLK_A / 16; ++k)
        s += ws2[(row * (NBLK_A / 16) + k) * 16 + e];
    red[row][e] = s;
    __syncthreads();
    if (tid < 16) {
        float t2 = 0.f;
        #pragma unroll
        for (int r = 0; r < 16; ++r) t2 += red[r][tid];
        tot[tid] = t2;
    }
    __syncthreads();
    if (tid == 0) {
        float s2 = 0.f;
        #pragma unroll
        for (int e2 = 0; e2 < NE; ++e2) {
            const float ef = tot[NE + e2] / (float)(NTOK * 2);  // expert_frac
            const float rf = tot[e2] / (float)NTOK;             // router_frac
            s2 += ef * rf;
        }
        out[4 * NTOK] = (float)NE * s2 * AUX_COEF;
    }
}

extern "C" void kernel_launch(void* const* d_in, const int* in_sizes, int n_in,
                              void* d_out, int out_size, void* d_ws, size_t ws_size,
                              hipStream_t stream)
{
    const float* hs = (const float*)d_in[0];   // [4,4096,2048] f32
    const float* gw = (const float*)d_in[1];   // [8,2048] f32
    float* out = (float*)d_out;                // 32768 rw | 32768 idx | 1 aux
    float* ws2 = (float*)d_ws;                 // [1024][16] aux partials

    hipLaunchKernelGGL(router_fused, dim3(NBLK_A), dim3(512), 0, stream,
                       hs, gw, out, ws2);
    hipLaunchKernelGGL(router_aux2, dim3(1), dim3(256), 0, stream, ws2, out);
}

// Round 13
// 53.755 us; speedup vs baseline: 1.0487x; 1.0487x over previous
//
#include <hip/hip_runtime.h>

#define NE 8               // experts
#define H4 512             // float4 per token row (2048 floats)
#define NTOK 16384         // 4 * 4096 tokens
#define QK 2               // K halves, one per 2-wave team
#define ITQ (8 / QK)       // 64-col it-steps per half = 4
#define TPW 4              // tokens per wave
#define TPB 8              // tokens per block (2 waves x TPW, x2 teams)
#define NBLK_A (NTOK / TPB)  // 2048 blocks
#define AUX_COEF 0.01f

typedef float f4v __attribute__((ext_vector_type(4)));

// 8-leaf static-index select (rule #20: no runtime array indexing)
#define SEL8(A) ((e2 & 4) ? ((e2 & 2) ? ((e2 & 1) ? A[7] : A[6])   \
                                      : ((e2 & 1) ? A[5] : A[4]))  \
                          : ((e2 & 2) ? ((e2 & 1) ? A[3] : A[2])   \
                                      : ((e2 & 1) ? A[1] : A[0])))

// Fused router in R11's proven shape: 256-thread blocks, 4 waves.
// Waves 0-1 = K-half 0, waves 2-3 = K-half 1; each wave's streaming loop is
// byte-identical to R11's kernel A. Halves combine via 512 B LDS, every
// thread redundantly finishes its token (32 thr/token), writers emit
// outputs + per-block aux partials. Kernel B and part[] traffic eliminated.
__global__ __launch_bounds__(256)
void router_fused(const float* __restrict__ hs, const float* __restrict__ gw,
                  float* __restrict__ out, float* __restrict__ ws2)
{
    __shared__ float comb[QK * TPB * NE];    // 2 x 8 x 8 floats = 512 B
    __shared__ float auxS[TPB][16];

    const int tid  = threadIdx.x;
    const int wave = tid >> 6, lane = tid & 63;
    const int q    = wave >> 1;              // K-half team (0/1)
    const int wv   = wave & 1;               // wave within team
    const int tok0 = blockIdx.x * TPB + wv * TPW;

    const f4v* __restrict__ hs4 = (const f4v*)hs;
    const f4v* __restrict__ gw4 = (const f4v*)gw;

    float acc[TPW][NE];
    #pragma unroll
    for (int r = 0; r < TPW; ++r)
        #pragma unroll
        for (int e = 0; e < NE; ++e) acc[r][e] = 0.f;

    #pragma unroll
    for (int it = 0; it < ITQ; ++it) {
        const int col = q * (H4 / QK) + it * 64 + lane;
        f4v h[TPW];
        #pragma unroll
        for (int r = 0; r < TPW; ++r)
            h[r] = hs4[(size_t)(tok0 + r) * H4 + col];
        f4v g[NE];
        #pragma unroll
        for (int e = 0; e < NE; ++e) g[e] = gw4[e * H4 + col];
        #pragma unroll
        for (int r = 0; r < TPW; ++r)
            #pragma unroll
            for (int e = 0; e < NE; ++e)
                acc[r][e] += h[r].x * g[e].x + h[r].y * g[e].y
                           + h[r].z * g[e].z + h[r].w * g[e].w;
    }

    // butterfly: every lane gets the full half-dot for all 32 (r,e)
    #pragma unroll
    for (int r = 0; r < TPW; ++r)
        #pragma unroll
        for (int e = 0; e < NE; ++e) {
            float v = acc[r][e];
            #pragma unroll
            for (int s = 32; s > 0; s >>= 1) v += __shfl_xor(v, s, 64);
            acc[r][e] = v;
        }

    // lanes 0..31: one (token,expert) half-partial each -> LDS
    // (32 consecutive floats per wave -> banks 0..31, conflict-free)
    {
        const int r2 = (lane >> 3) & 3, e2 = lane & 7;
        const float v = (r2 & 2) ? ((r2 & 1) ? SEL8(acc[3]) : SEL8(acc[2]))
                                 : ((r2 & 1) ? SEL8(acc[1]) : SEL8(acc[0]));
        if (lane < 32)
            comb[(q * TPB + wv * TPW + r2) * NE + e2] = v;
    }
    __syncthreads();

    // every thread finishes token t = tid>>5 redundantly (32 threads/token)
    const int t = tid >> 5;
    const float4* comb4 = (const float4*)comb;
    float lg[NE];
    {
        const float4 a0 = comb4[t * 2],             a1 = comb4[t * 2 + 1];
        const float4 b0 = comb4[(TPB + t) * 2],     b1 = comb4[(TPB + t) * 2 + 1];
        lg[0]=a0.x+b0.x; lg[1]=a0.y+b0.y; lg[2]=a0.z+b0.z; lg[3]=a0.w+b0.w;
        lg[4]=a1.x+b1.x; lg[5]=a1.y+b1.y; lg[6]=a1.z+b1.z; lg[7]=a1.w+b1.w;
    }

    float m = lg[0];
    #pragma unroll
    for (int e = 1; e < NE; ++e) m = fmaxf(m, lg[e]);
    float p[NE];
    float s = 0.f;
    #pragma unroll
    for (int e = 0; e < NE; ++e) { p[e] = __expf(lg[e] - m); s += p[e]; }
    const float inv = 1.f / s;

    // top-2 on probs; strict '>' keeps lowest index on ties (lax.top_k order)
    float v0 = -1.f; int i0 = 0;
    #pragma unroll
    for (int e = 0; e < NE; ++e) { if (p[e] > v0) { v0 = p[e]; i0 = e; } }
    float v1 = -1.f; int i1 = 0;
    #pragma unroll
    for (int e = 0; e < NE; ++e) { if (e != i0 && p[e] > v1) { v1 = p[e]; i1 = e; } }

    if ((tid & 31) == 0) {
        const int tok = blockIdx.x * TPB + t;
        float2* __restrict__ o2 = (float2*)out;
        const float wsum = v0 + v1;
        o2[tok]        = make_float2(v0 / wsum, v1 / wsum);
        o2[NTOK + tok] = make_float2((float)i0, (float)i1);
        #pragma unroll
        for (int e = 0; e < NE; ++e) {
            auxS[t][e]      = p[e] * inv;
            auxS[t][NE + e] = ((i0 == e) ? 1.f : 0.f) + ((i1 == e) ? 1.f : 0.f);
        }
    }
    __syncthreads();

    // per-block aux partial: sum 8 token-rows -> ws2[block][0..15]
    if (tid < 16) {
        float sum = 0.f;
        #pragma unroll
        for (int t2 = 0; t2 < TPB; ++t2) sum += auxS[t2][tid];
        ws2[blockIdx.x * 16 + tid] = sum;
    }
}

// Reduce 2048 x 16 partials -> aux scalar
__global__ __launch_bounds__(256)
void router_aux2(const float* __restrict__ ws2, float* __restrict__ out)
{
    __shared__ float red[16][16];
    __shared__ float tot[16];
    const int tid = threadIdx.x;
    const int e = tid & 15, row = tid >> 4;      // 16 rows x 16 experts-slots
    float s = 0.f;
    #pragma unroll 4
    for (int k = 0; k < NBLK_A / 16; ++k)
        s += ws2[(row * (NBLK_A / 16) + k) * 16 + e];
    red[row][e] = s;
    __syncthreads();
    if (tid < 16) {
        float t2 = 0.f;
        #pragma unroll
        for (int r = 0; r < 16; ++r) t2 += red[r][tid];
        tot[tid] = t2;
    }
    __syncthreads();
    if (tid == 0) {
        float s2 = 0.f;
        #pragma unroll
        for (int e2 = 0; e2 < NE; ++e2) {
            const float ef = tot[NE + e2] / (float)(NTOK * 2);  // expert_frac
            const float rf = tot[e2] / (float)NTOK;             // router_frac
            s2 += ef * rf;
        }
        out[4 * NTOK] = (float)NE * s2 * AUX_COEF;
    }
}

extern "C" void kernel_launch(void* const* d_in, const int* in_sizes, int n_in,
                              void* d_out, int out_size, void* d_ws, size_t ws_size,
                              hipStream_t stream)
{
    const float* hs = (const float*)d_in[0];   // [4,4096,2048] f32
    const float* gw = (const float*)d_in[1];   // [8,2048] f32
    float* out = (float*)d_out;                // 32768 rw | 32768 idx | 1 aux
    float* ws2 = (float*)d_ws;                 // [2048][16] aux partials

    hipLaunchKernelGGL(router_fused, dim3(NBLK_A), dim3(256), 0, stream,
                       hs, gw, out, ws2);
    hipLaunchKernelGGL(router_aux2, dim3(1), dim3(256), 0, stream, ws2, out);
}

// Round 14
// 45.236 us; speedup vs baseline: 1.2463x; 1.1883x over previous
//
#include <hip/hip_runtime.h>

#define NE 8               // experts
#define H4 512             // float4 per token row (2048 floats)
#define NTOK 16384         // 4 * 4096 tokens
#define QK 2               // K halves
#define ITQ (8 / QK)       // 64-col it-steps per half = 4
#define TPW 8              // tokens per wave (g-bytes : h-bytes now 1:1)
#define TPB 32             // tokens per block (4 waves x TPW)
#define NBLK_B 64          // finish-kernel blocks (16384 / 256)
#define AUX_COEF 0.01f

// ws layout (floats): part[QK][NTOK][NE] | ws2[NBLK_B*16]
#define WS2_OFF (QK * NTOK * NE)

typedef float f4v __attribute__((ext_vector_type(4)));

// 8-leaf static-index select (rule #20: no runtime array indexing)
#define SEL8(A) ((e2 & 4) ? ((e2 & 2) ? ((e2 & 1) ? A[7] : A[6])   \
                                      : ((e2 & 1) ? A[5] : A[4]))  \
                          : ((e2 & 2) ? ((e2 & 1) ? A[3] : A[2])   \
                                      : ((e2 & 1) ? A[1] : A[0])))

// Kernel A (hot): streaming partial GEMV, R11 macro-shape (uncoupled
// 256-thread blocks, no LDS, no barriers, separate finish kernel).
// TPW=8: per wave 8 tokens x 1024 cols -> gate bytes = hidden bytes
// (was 2:1), VMEM issue per streamed byte halved. All 64 lanes store
// one (token,expert) partial -> a single 256 B contiguous store/wave.
__global__ __launch_bounds__(256)
void router_partial(const float* __restrict__ hs, const float* __restrict__ gw,
                    float* __restrict__ part)
{
    const int tid  = threadIdx.x;
    const int wave = tid >> 6, lane = tid & 63;
    const int q    = blockIdx.x & (QK - 1);
    const int tg   = blockIdx.x >> 1;            // log2(QK)
    const int tok0 = tg * TPB + wave * TPW;      // this wave's first token

    const f4v* __restrict__ hs4 = (const f4v*)hs;
    const f4v* __restrict__ gw4 = (const f4v*)gw;

    float acc[TPW][NE];
    #pragma unroll
    for (int r = 0; r < TPW; ++r)
        #pragma unroll
        for (int e = 0; e < NE; ++e) acc[r][e] = 0.f;

    #pragma unroll
    for (int it = 0; it < ITQ; ++it) {
        const int col = q * (H4 / QK) + it * 64 + lane;
        f4v h[TPW];
        #pragma unroll
        for (int r = 0; r < TPW; ++r)
            h[r] = hs4[(size_t)(tok0 + r) * H4 + col];
        f4v g[NE];
        #pragma unroll
        for (int e = 0; e < NE; ++e) g[e] = gw4[e * H4 + col];
        #pragma unroll
        for (int r = 0; r < TPW; ++r)
            #pragma unroll
            for (int e = 0; e < NE; ++e)
                acc[r][e] += h[r].x * g[e].x + h[r].y * g[e].y
                           + h[r].z * g[e].z + h[r].w * g[e].w;
    }

    // butterfly: every lane gets the full half-dot for all 64 (r,e)
    #pragma unroll
    for (int r = 0; r < TPW; ++r)
        #pragma unroll
        for (int e = 0; e < NE; ++e) {
            float v = acc[r][e];
            #pragma unroll
            for (int s = 32; s > 0; s >>= 1) v += __shfl_xor(v, s, 64);
            acc[r][e] = v;
        }

    // each lane stores one (token r2, expert e2) partial: 256 B/wave coalesced
    const int r2 = lane >> 3, e2 = lane & 7;
    const float v =
        (r2 & 4) ? ((r2 & 2) ? ((r2 & 1) ? SEL8(acc[7]) : SEL8(acc[6]))
                             : ((r2 & 1) ? SEL8(acc[5]) : SEL8(acc[4])))
                 : ((r2 & 2) ? ((r2 & 1) ? SEL8(acc[3]) : SEL8(acc[2]))
                             : ((r2 & 1) ? SEL8(acc[1]) : SEL8(acc[0])));
    part[((size_t)q * NTOK + tok0 + r2) * NE + e2] = v;
}

// Kernel B: one thread per token. Sum QK partials (fixed order),
// softmax + top-2 + renorm, coalesced float2 outputs, per-block aux partial.
__global__ __launch_bounds__(256)
void router_finish(const float* __restrict__ part, float* __restrict__ out,
                   float* __restrict__ ws2)
{
    __shared__ float red[4][2 * NE];
    const int tid = threadIdx.x;
    const int t   = blockIdx.x * 256 + tid;      // token
    const float4* __restrict__ p4 = (const float4*)part;

    float lg[NE];
    {
        float4 a = p4[(size_t)t * 2],  b = p4[(size_t)t * 2 + 1];
        lg[0]=a.x; lg[1]=a.y; lg[2]=a.z; lg[3]=a.w;
        lg[4]=b.x; lg[5]=b.y; lg[6]=b.z; lg[7]=b.w;
    }
    #pragma unroll
    for (int q = 1; q < QK; ++q) {
        float4 a = p4[((size_t)q * NTOK + t) * 2];
        float4 b = p4[((size_t)q * NTOK + t) * 2 + 1];
        lg[0]+=a.x; lg[1]+=a.y; lg[2]+=a.z; lg[3]+=a.w;
        lg[4]+=b.x; lg[5]+=b.y; lg[6]+=b.z; lg[7]+=b.w;
    }

    float m = lg[0];
    #pragma unroll
    for (int e = 1; e < NE; ++e) m = fmaxf(m, lg[e]);
    float p[NE];
    float s = 0.f;
    #pragma unroll
    for (int e = 0; e < NE; ++e) { p[e] = __expf(lg[e] - m); s += p[e]; }
    const float inv = 1.f / s;

    // top-2 on probs; strict '>' keeps lowest index on ties (lax.top_k order)
    float v0 = -1.f; int i0 = 0;
    #pragma unroll
    for (int e = 0; e < NE; ++e) { if (p[e] > v0) { v0 = p[e]; i0 = e; } }
    float v1 = -1.f; int i1 = 0;
    #pragma unroll
    for (int e = 0; e < NE; ++e) { if (e != i0 && p[e] > v1) { v1 = p[e]; i1 = e; } }

    float2* __restrict__ o2 = (float2*)out;
    const float wsum = v0 + v1;
    o2[t]        = make_float2(v0 / wsum, v1 / wsum);
    o2[NTOK + t] = make_float2((float)i0, (float)i1);

    // aux partials: every thread owns exactly one token
    float qv[NE], c[NE];
    #pragma unroll
    for (int e = 0; e < NE; ++e) {
        qv[e] = p[e] * inv;
        c[e]  = ((i0 == e) ? 1.f : 0.f) + ((i1 == e) ? 1.f : 0.f);
    }
    #pragma unroll
    for (int e = 0; e < NE; ++e) {
        #pragma unroll
        for (int sh = 32; sh > 0; sh >>= 1) {
            qv[e] += __shfl_xor(qv[e], sh, 64);
            c[e]  += __shfl_xor(c[e],  sh, 64);
        }
    }
    const int wave = tid >> 6, lane = tid & 63;
    if (lane == 0) {
        #pragma unroll
        for (int e = 0; e < NE; ++e) {
            red[wave][e]      = qv[e];
            red[wave][NE + e] = c[e];
        }
    }
    __syncthreads();
    if (tid < 2 * NE) {
        float sum = red[0][tid] + red[1][tid] + red[2][tid] + red[3][tid];
        ws2[blockIdx.x * 2 * NE + tid] = sum;
    }
}

// Kernel C: reduce 64 x 16 partials -> aux scalar
__global__ __launch_bounds__(128)
void router_aux2(const float* __restrict__ ws2, float* __restrict__ out)
{
    __shared__ float red[8][16];
    __shared__ float tot[16];
    const int tid = threadIdx.x;
    const int e = tid & 15, row = tid >> 4;      // 8 rows x 16
    float s = 0.f;
    #pragma unroll
    for (int k = 0; k < NBLK_B / 8; ++k)
        s += ws2[(row * (NBLK_B / 8) + k) * 16 + e];
    red[row][e] = s;
    __syncthreads();
    if (tid < 16) {
        float t2 = 0.f;
        #pragma unroll
        for (int r = 0; r < 8; ++r) t2 += red[r][tid];
        tot[tid] = t2;
    }
    __syncthreads();
    if (tid == 0) {
        float s2 = 0.f;
        #pragma unroll
        for (int e2 = 0; e2 < NE; ++e2) {
            const float ef = tot[NE + e2] / (float)(NTOK * 2);  // expert_frac
            const float rf = tot[e2] / (float)NTOK;             // router_frac
            s2 += ef * rf;
        }
        out[4 * NTOK] = (float)NE * s2 * AUX_COEF;
    }
}

extern "C" void kernel_launch(void* const* d_in, const int* in_sizes, int n_in,
                              void* d_out, int out_size, void* d_ws, size_t ws_size,
                              hipStream_t stream)
{
    const float* hs = (const float*)d_in[0];   // [4,4096,2048] f32
    const float* gw = (const float*)d_in[1];   // [8,2048] f32
    float* out  = (float*)d_out;               // 32768 rw | 32768 idx | 1 aux
    float* part = (float*)d_ws;                // [QK][16384][8] partial logits
    float* ws2  = (float*)d_ws + WS2_OFF;      // [64][16] aux partials

    hipLaunchKernelGGL(router_partial, dim3(NTOK / TPB * QK), dim3(256), 0,
                       stream, hs, gw, part);
    hipLaunchKernelGGL(router_finish, dim3(NBLK_B), dim3(256), 0,
                       stream, part, out, ws2);
    hipLaunchKernelGGL(router_aux2, dim3(1), dim3(128), 0, stream, ws2, out);
}